// Round 5
// baseline (167.070 us; speedup 1.0000x reference)
//
#include <hip/hip_runtime.h>
#include <hip/hip_bf16.h>

// GatedMoE: B=8, T=4096, D=128, E=16, TOP_K=2 (f32 in/out, bf16 MFMA inside)
// out = concat(weighted_avg [NTOK*128] f32, consensus [NTOK] f32)
// R5 structure: tokens grouped by expert PAIR (top1*16+top2). One fused kernel
// computes y1,y2 via MFMA and finishes avg/var/consensus in-register.
#define NTOK 32768
#define DD 128
#define NE 16
#define NPAIR 256
#define CSTRIDE 32   // pad each pair counter to its own 128B line

// ws layout (bytes); total ~48 MiB
#define OFF_COUNTS 0                     // NPAIR*CSTRIDE ints = 32 KiB
#define OFF_TOKW   (64*1024)             // NTOK*2 f32  = 256 KiB
#define OFF_XB     (1*1024*1024)         // NTOK*128 bf16 = 8 MiB
#define OFF_EWT    (9*1024*1024)         // NE*128*128 bf16 = 512 KiB
#define OFF_LISTS  (16*1024*1024)        // NPAIR*NTOK int = 32 MiB

typedef __attribute__((ext_vector_type(8))) short bf16x8;
typedef __attribute__((ext_vector_type(4))) float f32x4;

static __device__ inline ushort f2bf(float f) {      // RNE f32 -> bf16 bits
    uint u = __builtin_bit_cast(uint, f);
    u = u + 0x7FFFu + ((u >> 16) & 1u);
    return (ushort)(u >> 16);
}

// ---------------- Kernel 0: Ew f32[k][o] -> EwT bf16[o][k] ------------------
// grid = 256 blocks (16 experts x 16 tiles of 32x32), 256 threads. (validated R4)
__global__ __launch_bounds__(256) void ewt_kernel(
    const float* __restrict__ Ew, ushort* __restrict__ ewT)
{
    __shared__ float tile[32][33];
    const int b = blockIdx.x;
    const int e = b >> 4, ki = ((b >> 2) & 3) * 32, oi = (b & 3) * 32;
    const int tid = threadIdx.x;
    const int r = tid >> 3, c4 = (tid & 7) * 4;
    const float4 v = *(const float4*)(Ew + (size_t)e * DD * DD + (ki + r) * DD + oi + c4);
    tile[r][c4 + 0] = v.x; tile[r][c4 + 1] = v.y;
    tile[r][c4 + 2] = v.z; tile[r][c4 + 3] = v.w;
    __syncthreads();
    const int o = tid >> 3, k4 = (tid & 7) * 4;
    ushort4 s;
    s.x = f2bf(tile[k4 + 0][o]);
    s.y = f2bf(tile[k4 + 1][o]);
    s.z = f2bf(tile[k4 + 2][o]);
    s.w = f2bf(tile[k4 + 3][o]);
    *(ushort4*)(ewT + (size_t)e * DD * DD + (oi + o) * DD + ki + k4) = s;
}

// ---------------- Kernel 1: gating + x->bf16 + pair-list build ---------------
// 4 lanes per token; 256 thr = 64 tokens/block; grid 512. LDS-aggregated
// 256 pair counters, global atomics only for pairs touched by the block.
__global__ __launch_bounds__(256) void gate_kernel(
    const float* __restrict__ x, const float* __restrict__ Wg,
    const float* __restrict__ bg,
    int* __restrict__ counts, int* __restrict__ lists, float* __restrict__ tokw,
    ushort* __restrict__ xb)
{
    __shared__ float sWg[DD * NE];   // 8 KiB
    __shared__ float sBg[NE];
    __shared__ int   sCnt[NPAIR];
    __shared__ int   sBase[NPAIR];
    const int tid = threadIdx.x;
    for (int i = tid; i < DD * NE; i += 256) sWg[i] = Wg[i];
    if (tid < NE) sBg[tid] = bg[tid];
    sCnt[tid] = 0;
    __syncthreads();

    const int t = blockIdx.x * 64 + (tid >> 2);
    const int g = tid & 3;
    const float* xt = x + (size_t)t * DD;
    ushort*      xo = xb + (size_t)t * DD;

    float logits[NE];
    #pragma unroll
    for (int e = 0; e < NE; ++e) logits[e] = 0.0f;

    // lane g handles dims {g*4 + i*16 .. +3}, i=0..7
    #pragma unroll
    for (int i = 0; i < 8; ++i) {
        const int d0 = g * 4 + i * 16;
        float4 v = ((const float4*)xt)[g + i * 4];
        const float* w0 = &sWg[(d0 + 0) * NE];
        const float* w1 = &sWg[(d0 + 1) * NE];
        const float* w2 = &sWg[(d0 + 2) * NE];
        const float* w3 = &sWg[(d0 + 3) * NE];
        #pragma unroll
        for (int e = 0; e < NE; ++e) {
            float a = logits[e];
            a = fmaf(v.x, w0[e], a);
            a = fmaf(v.y, w1[e], a);
            a = fmaf(v.z, w2[e], a);
            a = fmaf(v.w, w3[e], a);
            logits[e] = a;
        }
        ushort4 s; s.x = f2bf(v.x); s.y = f2bf(v.y); s.z = f2bf(v.z); s.w = f2bf(v.w);
        *(ushort4*)(xo + d0) = s;
    }

    #pragma unroll
    for (int e = 0; e < NE; ++e) {
        float a = logits[e];
        a += __shfl_xor(a, 1);
        a += __shfl_xor(a, 2);
        logits[e] = a + sBg[e];
    }

    float m = logits[0];
    #pragma unroll
    for (int e = 1; e < NE; ++e) m = fmaxf(m, logits[e]);
    float Z = 0.0f;
    #pragma unroll
    for (int e = 0; e < NE; ++e) Z += expf(logits[e] - m);

    int i1 = 0; float l1 = logits[0];
    #pragma unroll
    for (int e = 1; e < NE; ++e) if (logits[e] > l1) { l1 = logits[e]; i1 = e; }
    int i2 = -1; float l2 = -3.4e38f;
    #pragma unroll
    for (int e = 0; e < NE; ++e) if (e != i1 && logits[e] > l2) { l2 = logits[e]; i2 = e; }

    int slot = 0, pair = 0;
    if (g == 0) {
        float p1 = expf(l1 - m) / Z;
        float p2 = expf(l2 - m) / Z;
        float s  = p1 + p2 + 1e-6f;
        tokw[t * 2 + 0] = p1 / s;
        tokw[t * 2 + 1] = p2 / s;
        pair = i1 * NE + i2;
        slot = atomicAdd(&sCnt[pair], 1);
    }
    __syncthreads();
    if (sCnt[tid] > 0) sBase[tid] = atomicAdd(&counts[tid * CSTRIDE], sCnt[tid]);
    __syncthreads();
    if (g == 0)
        lists[pair * NTOK + sBase[pair] + slot] = t;
}

// ---------------- Kernel 2: fused pair GEMM + combine ------------------------
// grid (4, 256): pair = blockIdx.y, grid-stride over 128-token tiles.
// block 256 = 4 waves; wave = 32 tokens (two 16-token groups) x both experts.
// No LDS, no barriers. A-frag = EwT rows, B-frag = xb rows (R4-validated);
// lane owns token lane&15 of its group, outputs o = n*16 + kg*4 + reg.
__global__ __launch_bounds__(256) void moe_kernel(
    const ushort* __restrict__ xb, const ushort* __restrict__ ewT,
    const int* __restrict__ counts, const int* __restrict__ lists,
    const float* __restrict__ tokw,
    float* __restrict__ avg_out, float* __restrict__ cons_out)
{
    const int pair = blockIdx.y;
    const int ea = pair >> 4, eb = pair & 15;
    const int count = counts[pair * CSTRIDE];

    const int tid  = threadIdx.x;
    const int lane = tid & 63, wv = tid >> 6;
    const int row  = lane & 15;          // token within group == D column
    const int kg   = lane >> 4;          // k-group 0..3 == output sub-row

    const ushort* ewa = ewT + (size_t)ea * DD * DD;
    const ushort* ewb = ewT + (size_t)eb * DD * DD;

    for (int tile = blockIdx.x; tile * 128 < count; tile += 4) {
        const int base = tile * 128 + wv * 32;
        const int idx0 = base + row, idx1 = base + 16 + row;
        const int t0 = (idx0 < count) ? lists[pair * NTOK + idx0] : -1;
        const int t1 = (idx1 < count) ? lists[pair * NTOK + idx1] : -1;

        const ushort* xr0 = xb + (size_t)(t0 < 0 ? 0 : t0) * DD;
        const ushort* xr1 = xb + (size_t)(t1 < 0 ? 0 : t1) * DD;
        bf16x8 xf0[4], xf1[4];
        #pragma unroll
        for (int k = 0; k < 4; ++k) {
            xf0[k] = *(const bf16x8*)(xr0 + k * 32 + kg * 8);
            xf1[k] = *(const bf16x8*)(xr1 + k * 32 + kg * 8);
        }
        const int tw0 = (t0 < 0 ? 0 : t0), tw1 = (t1 < 0 ? 0 : t1);
        const float w1a = tokw[tw0 * 2 + 0], w2a = tokw[tw0 * 2 + 1];
        const float w1b = tokw[tw1 * 2 + 0], w2b = tokw[tw1 * 2 + 1];

        f32x4 aA0[8], aA1[8], aB0[8], aB1[8];
        #pragma unroll
        for (int n = 0; n < 8; ++n) {
            aA0[n] = (f32x4)(0.0f); aA1[n] = (f32x4)(0.0f);
            aB0[n] = (f32x4)(0.0f); aB1[n] = (f32x4)(0.0f);
        }

        #pragma unroll
        for (int n = 0; n < 8; ++n) {
            const ushort* ra = ewa + (size_t)(n * 16 + row) * DD + kg * 8;
            const ushort* rb = ewb + (size_t)(n * 16 + row) * DD + kg * 8;
            #pragma unroll
            for (int k = 0; k < 4; ++k) {
                bf16x8 efa = *(const bf16x8*)(ra + k * 32);
                bf16x8 efb = *(const bf16x8*)(rb + k * 32);
                aA0[n] = __builtin_amdgcn_mfma_f32_16x16x32_bf16(efa, xf0[k], aA0[n], 0, 0, 0);
                aA1[n] = __builtin_amdgcn_mfma_f32_16x16x32_bf16(efa, xf1[k], aA1[n], 0, 0, 0);
                aB0[n] = __builtin_amdgcn_mfma_f32_16x16x32_bf16(efb, xf0[k], aB0[n], 0, 0, 0);
                aB1[n] = __builtin_amdgcn_mfma_f32_16x16x32_bf16(efb, xf1[k], aB1[n], 0, 0, 0);
            }
        }

        // combine in-register: avg = w1*yA + w2*yB ; var accum per lane
        float v0 = 0.0f, v1 = 0.0f;
        #pragma unroll
        for (int n = 0; n < 8; ++n) {
            float4 av0, av1;
            float* p0 = (float*)&av0; float* p1 = (float*)&av1;
            #pragma unroll
            for (int r = 0; r < 4; ++r) {
                float yA = aA0[n][r], yB = aB0[n][r];
                float a = w1a * yA + w2a * yB;
                p0[r] = a;
                float dA = yA - a, dB = yB - a;
                v0 = fmaf(w1a, dA * dA, fmaf(w2a, dB * dB, v0));
                float zA = aA1[n][r], zB = aB1[n][r];
                float b = w1b * zA + w2b * zB;
                p1[r] = b;
                float eA = zA - b, eB = zB - b;
                v1 = fmaf(w1b, eA * eA, fmaf(w2b, eB * eB, v1));
            }
            if (t0 >= 0) *(float4*)(avg_out + (size_t)t0 * DD + n * 16 + kg * 4) = av0;
            if (t1 >= 0) *(float4*)(avg_out + (size_t)t1 * DD + n * 16 + kg * 4) = av1;
        }
        // sum variance over the 4 kg-lanes of the same token
        v0 += __shfl_xor(v0, 16); v0 += __shfl_xor(v0, 32);
        v1 += __shfl_xor(v1, 16); v1 += __shfl_xor(v1, 32);
        if (kg == 0) {
            if (t0 >= 0) cons_out[t0] = expf(-v0 * (1.0f / 128.0f));
            if (t1 >= 0) cons_out[t1] = expf(-v1 * (1.0f / 128.0f));
        }
    }
}

// ---------------- launcher ---------------------------------------------------
extern "C" void kernel_launch(void* const* d_in, const int* in_sizes, int n_in,
                              void* d_out, int out_size, void* d_ws, size_t ws_size,
                              hipStream_t stream)
{
    const float* x  = (const float*)d_in[0];
    const float* Wg = (const float*)d_in[1];
    const float* bg = (const float*)d_in[2];
    const float* Ew = (const float*)d_in[3];
    float* out = (float*)d_out;

    char* ws = (char*)d_ws;
    int*    counts = (int*)(ws + OFF_COUNTS);
    float*  tokw   = (float*)(ws + OFF_TOKW);
    ushort* xbuf   = (ushort*)(ws + OFF_XB);
    ushort* ewT    = (ushort*)(ws + OFF_EWT);
    int*    lists  = (int*)(ws + OFF_LISTS);

    hipMemsetAsync(counts, 0, NPAIR * CSTRIDE * sizeof(int), stream);

    ewt_kernel<<<256, 256, 0, stream>>>(Ew, ewT);
    gate_kernel<<<NTOK / 64, 256, 0, stream>>>(x, Wg, bg, counts, lists, tokw, xbuf);
    moe_kernel<<<dim3(4, NPAIR), 256, 0, stream>>>(xbuf, ewT, counts, lists, tokw,
                                                   out, out + (size_t)NTOK * DD);
}